// Round 6
// baseline (194.327 us; speedup 1.0000x reference)
//
#include <hip/hip_runtime.h>
#include <math.h>

#pragma clang fp contract(off)

#define BN 4
#define SX 512
#define SY 512
#define NPIX (BN * SX * SY)
#define MU 5
#define MB (1024 * 1024)
#define SOB_BLOCKS (NPIX / 2048)   // 512 sobel blocks (8 px/thread)

struct DogW  { float g[7];  float tw; };
struct FdogW { float g[10]; float tw; };

// tanh via expm1 identity: tanh(d) = expm1(2|d|) / (expm1(2|d|) + 2), odd.
__device__ __forceinline__ float fast_tanh_f32(float dF) {
    double d = (double)dF;
    double y = fabs(d);
    double t = expm1(2.0 * y);
    double r = t / (t + 2.0);
    if (y > 350.0) r = 1.0;
    return (float)copysign(r, d);
}

__device__ __forceinline__ float img_at(const float* __restrict__ img, int b, int x, int y) {
    if (x < 0 || x >= SX || y < 0 || y >= SY) return 0.0f;
    return img[(size_t)b * SX * SY + (size_t)x * SY + y];
}

// Stage 1: Sobel -> mag (unnormalized), initial tangent, per-block max.
// 8 px/thread: 6 float4 row loads + 6 guarded scalars = 1.31 ld/px, 2x ILP.
// Per-pixel expression order identical to scalar version -> bit-exact.
__global__ __launch_bounds__(256) void k_sobel(const float* __restrict__ img,
                                               float* __restrict__ mag,
                                               float2* __restrict__ tang,
                                               float* __restrict__ partial) {
#pragma clang fp contract(off)
    int tid = threadIdx.x;
    size_t pixbase = (size_t)blockIdx.x * 2048 + (size_t)tid * 8;
    int b  = (int)(pixbase >> 18);          // / (512*512)
    int p  = (int)(pixbase & 262143);
    int xi = p >> 9;
    int yi = p & 511;                        // multiple of 8
    size_t base = (size_t)b * SX * SY;
    size_t idx  = base + (size_t)xi * SY + yi;

    bool xm = (xi - 1 >= 0);
    bool xp = (xi + 1 < SX);
    const float* rowm = img + base + (size_t)(xi - 1) * SY;
    const float* row0 = img + base + (size_t)xi * SY;
    const float* rowp = img + base + (size_t)(xi + 1) * SY;

    float4 a4a = make_float4(0.f,0.f,0.f,0.f), a4b = make_float4(0.f,0.f,0.f,0.f);
    float4 c4a = make_float4(0.f,0.f,0.f,0.f), c4b = make_float4(0.f,0.f,0.f,0.f);
    float4 b4a = *(const float4*)(row0 + yi);
    float4 b4b = *(const float4*)(row0 + yi + 4);
    if (xm) { a4a = *(const float4*)(rowm + yi); a4b = *(const float4*)(rowm + yi + 4); }
    if (xp) { c4a = *(const float4*)(rowp + yi); c4b = *(const float4*)(rowp + yi + 4); }

    float aL = 0.f, aR = 0.f, bL = 0.f, bR = 0.f, cL = 0.f, cR = 0.f;
    if (yi > 0) {
        bL = row0[yi - 1];
        if (xm) aL = rowm[yi - 1];
        if (xp) cL = rowp[yi - 1];
    }
    if (yi + 8 < SY) {
        bR = row0[yi + 8];
        if (xm) aR = rowm[yi + 8];
        if (xp) cR = rowp[yi + 8];
    }

    float a[10]  = { aL, a4a.x, a4a.y, a4a.z, a4a.w, a4b.x, a4b.y, a4b.z, a4b.w, aR };
    float bb[10] = { bL, b4a.x, b4a.y, b4a.z, b4a.w, b4b.x, b4b.y, b4b.z, b4b.w, bR };
    float c[10]  = { cL, c4a.x, c4a.y, c4a.z, c4a.w, c4b.x, c4b.y, c4b.z, c4b.w, cR };

    float m8[8];
    float tg[16];
    float wm = 0.0f;
#pragma unroll
    for (int j = 0; j < 8; ++j) {
        float v00 = a[j];
        float v01 = a[j + 1];
        float v02 = a[j + 2];
        float v10 = bb[j];
        float v12 = bb[j + 2];
        float v20 = c[j];
        float v21 = c[j + 1];
        float v22 = c[j + 2];

        float s0 = (-1.0f * v00);
        s0 = s0 + (-2.0f * v01);
        s0 = s0 + (-1.0f * v02);
        s0 = s0 + ( 1.0f * v20);
        s0 = s0 + ( 2.0f * v21);
        s0 = s0 + ( 1.0f * v22);
        float s1 = (-1.0f * v00);
        s1 = s1 + ( 1.0f * v02);
        s1 = s1 + (-2.0f * v10);
        s1 = s1 + ( 2.0f * v12);
        s1 = s1 + (-1.0f * v20);
        s1 = s1 + ( 1.0f * v22);

        float m = sqrtf((s0 * s0) + (s1 * s1));
        float tx = -s1, ty = s0;
        float n = sqrtf((tx * tx) + (ty * ty));
        float d = (n == 0.0f) ? 1.0f : n;
        m8[j] = m;
        tg[2 * j]     = tx / d;
        tg[2 * j + 1] = ty / d;
        wm = fmaxf(wm, m);
    }
    ((float4*)(mag + idx))[0] = make_float4(m8[0], m8[1], m8[2], m8[3]);
    ((float4*)(mag + idx))[1] = make_float4(m8[4], m8[5], m8[6], m8[7]);
#pragma unroll
    for (int q = 0; q < 4; ++q)
        ((float4*)(tang + idx))[q] = make_float4(tg[4*q], tg[4*q+1], tg[4*q+2], tg[4*q+3]);

    for (int off = 32; off > 0; off >>= 1) wm = fmaxf(wm, __shfl_down(wm, off, 64));
    __shared__ float red[4];
    int lane = tid & 63;
    int wid  = tid >> 6;
    if (lane == 0) red[wid] = wm;
    __syncthreads();
    if (tid == 0)
        partial[blockIdx.x] = fmaxf(fmaxf(red[0], red[1]), fmaxf(red[2], red[3]));
}

// Fallback only: reduce partials -> global max bits (one block).
__global__ void k_reduce(const float* __restrict__ partial, unsigned int* __restrict__ maxbits) {
    float m = 0.0f;
    for (int i = threadIdx.x; i < SOB_BLOCKS; i += 256) m = fmaxf(m, partial[i]);
    for (int off = 32; off > 0; off >>= 1) m = fmaxf(m, __shfl_down(m, off, 64));
    __shared__ float red[4];
    int lane = threadIdx.x & 63;
    int wid  = threadIdx.x >> 6;
    if (lane == 0) red[wid] = m;
    __syncthreads();
    if (threadIdx.x == 0) {
        float bm = fmaxf(fmaxf(red[0], red[1]), fmaxf(red[2], red[3]));
        *maxbits = __float_as_uint(bm);
    }
}

// Fallback only: mag /= max(mag)
__global__ void k_norm(float* __restrict__ mag, const unsigned int* __restrict__ maxbits) {
    int i = blockIdx.x * blockDim.x + threadIdx.x;
    float mx = __uint_as_float(*maxbits);
    mag[i] = mag[i] / mx;
}

#define VTY 32
#define VTX 16

// Stage 2a (iteration 1 V-pass): computes the 5 TV tanh planes for its tile
// in LDS from staged raw mag (mx via redundant partial-reduce; expression
// tanh(m[x+k]/mx - m[x]/mx) identical to the old k_tanh -> bit-exact), writes
// them to global TV for iterations 2-3 (halo overlap = duplicate identical
// writes, benign), then runs the V-pass from LDS. Boundary plane entries are
// garbage but only ever read under the same nx<SX tap guards k_tanh relied on.
__global__ __launch_bounds__(256) void k_etf_v1(const float2* __restrict__ tsrc,
                                                float2* __restrict__ tdst,
                                                const float* __restrict__ mag,
                                                const float* __restrict__ partial,
                                                float* __restrict__ TV) {
#pragma clang fp contract(off)
    int ty  = threadIdx.x & 31;
    int txw = threadIdx.x >> 5;
    int y0 = blockIdx.x * VTY;
    int x0 = blockIdx.y * VTX;
    int b  = blockIdx.z;
    size_t base = (size_t)b * SX * SY;

    __shared__ __align__(16) float2 sT[VTX + 2 * MU][VTY];     // 26 x 32 f2 (6.5 KB)
    __shared__ __align__(16) float  sM[VTX + 2 * MU][VTY];     // 26 x 32 f  (3.3 KB)
    __shared__ __align__(16) float  sTV[5][VTX + MU][VTY];     // 5 x 21 x 32 (13.4 KB)
    __shared__ float red[4];

    int tid = threadIdx.x;
    // stage tsrc rows [x0-5, x0+21): 26 * 16 float4
    for (int i = tid; i < (VTX + 2 * MU) * (VTY / 4) * 2; i += 256) {
        int r = i >> 4;
        int c = i & 15;
        int gx = x0 - MU + r;
        if (gx >= 0 && gx < SX)
            ((float4*)&sT[r][0])[c] = ((const float4*)(tsrc + base + (size_t)gx * SY + y0))[c];
    }
    // stage raw mag rows [x0-5, x0+21): 26 * 8 float4
    for (int i = tid; i < (VTX + 2 * MU) * (VTY / 4); i += 256) {
        int r = i >> 3;
        int c = i & 7;
        int gx = x0 - MU + r;
        if (gx >= 0 && gx < SX)
            ((float4*)&sM[r][0])[c] = ((const float4*)(mag + base + (size_t)gx * SY + y0))[c];
    }
    // mx: redundant reduce of the 512 per-block partials (fmax exact)
    float m2 = 0.0f;
    for (int i = tid; i < SOB_BLOCKS; i += 256) m2 = fmaxf(m2, partial[i]);
    for (int off = 32; off > 0; off >>= 1) m2 = fmaxf(m2, __shfl_down(m2, off, 64));
    if ((tid & 63) == 0) red[tid >> 6] = m2;
    __syncthreads();
    const float mx = fmaxf(fmaxf(red[0], red[1]), fmaxf(red[2], red[3]));

    // build the 5 tanh planes (rows [x0-5, x0+16)) + write to global TV
    for (int i = tid; i < 5 * (VTX + MU) * VTY; i += 256) {
        int j   = i / ((VTX + MU) * VTY);
        int rem = i - j * ((VTX + MU) * VTY);
        int r   = rem >> 5;
        int c   = rem & 31;
        float nm = sM[r + j + 1][c] / mx;
        float cm = sM[r][c] / mx;
        float val = fast_tanh_f32(nm - cm);
        sTV[j][r][c] = val;
        int gx = x0 - MU + r;
        if (gx >= 0 && gx < SX)
            TV[(size_t)j * NPIX + base + (size_t)gx * SY + (y0 + c)] = val;
    }
    __syncthreads();

    int yi = y0 + ty;
#pragma unroll
    for (int sub = 0; sub < 2; ++sub) {
        int tx = txw + (sub << 3);
        int xi = x0 + tx;
        size_t idx = base + (size_t)xi * SY + yi;

        float2 ct = sT[tx + MU][ty];
        float sx = 0.0f, sy = 0.0f;
#pragma unroll
        for (int k = -MU; k <= MU; ++k) {
            int nx = xi + k;
            if (nx < 0 || nx >= SX) continue;
            float2 nt = sT[tx + MU + k][ty];
            float th;
            if (k > 0)      th =  sTV[k - 1][tx + MU][ty];
            else if (k < 0) th = -sTV[-k - 1][tx + MU + k][ty];
            else            th =  0.0f;
            float dot = (ct.x * nt.x) + (ct.y * nt.y);
            float w   = ((th + 1.0f) * dot) * 0.5f;
            sx = sx + (nt.x * w);
            sy = sy + (nt.y * w);
        }
        float n = sqrtf((sx * sx) + (sy * sy));
        float d = (n == 0.0f) ? 1.0f : n;
        tdst[idx] = make_float2(sx / d, sy / d);
    }
}

// Stage 2b (iteration 1 H-pass): builds the 5 TH planes for its row in LDS
// from staged raw mag (+ mx), writes them to global TH for iterations 2-3,
// then runs the H-pass. Bit-exact per the same argument as k_etf_v1.
__global__ __launch_bounds__(256) void k_etf_h1(const float2* __restrict__ tsrc,
                                                float2* __restrict__ tdst,
                                                const float* __restrict__ mag,
                                                const float* __restrict__ partial,
                                                float* __restrict__ TH) {
#pragma clang fp contract(off)
    int tid = threadIdx.x;
    int xi  = blockIdx.y;
    int b   = blockIdx.z;
    size_t base    = (size_t)b * SX * SY;
    size_t rowbase = base + (size_t)xi * SY;

    __shared__ __align__(16) float2 sT[SY];        // 4 KB
    __shared__ __align__(16) float  sMr[SY];       // 2 KB
    __shared__ __align__(16) float  sTH[5][SY];    // 10 KB
    __shared__ float red[4];

    ((float4*)sT)[tid] = ((const float4*)(tsrc + rowbase))[tid];
    for (int i = tid; i < SY / 4; i += 256)
        ((float4*)sMr)[i] = ((const float4*)(mag + rowbase))[i];

    float m2 = 0.0f;
    for (int i = tid; i < SOB_BLOCKS; i += 256) m2 = fmaxf(m2, partial[i]);
    for (int off = 32; off > 0; off >>= 1) m2 = fmaxf(m2, __shfl_down(m2, off, 64));
    if ((tid & 63) == 0) red[tid >> 6] = m2;
    __syncthreads();
    const float mx = fmaxf(fmaxf(red[0], red[1]), fmaxf(red[2], red[3]));

    // build TH planes (guard matches old k_tanh: only y+j+1 < SY written)
    for (int i = tid; i < 5 * SY; i += 256) {
        int j = i >> 9;
        int y = i & 511;
        if (y + j + 1 < SY) {
            float nm = sMr[y + j + 1] / mx;
            float cm = sMr[y] / mx;
            float val = fast_tanh_f32(nm - cm);
            sTH[j][y] = val;
            TH[(size_t)j * NPIX + rowbase + y] = val;
        }
    }
    __syncthreads();

#pragma unroll
    for (int half = 0; half < 2; ++half) {
        int yi = tid + half * 256;
        float2 ct = sT[yi];
        float sx = 0.0f, sy = 0.0f;
#pragma unroll
        for (int k = -MU; k <= MU; ++k) {
            int ny = yi + k;
            if (ny < 0 || ny >= SY) continue;
            float2 nt = sT[ny];
            float th;
            if (k > 0)      th =  sTH[k - 1][yi];
            else if (k < 0) th = -sTH[-k - 1][ny];
            else            th =  0.0f;
            float dot = (ct.x * nt.x) + (ct.y * nt.y);
            float w   = ((th + 1.0f) * dot) * 0.5f;
            sx = sx + (nt.x * w);
            sy = sy + (nt.y * w);
        }
        float n = sqrtf((sx * sx) + (sy * sy));
        float d = (n == 0.0f) ? 1.0f : n;
        tdst[rowbase + yi] = make_float2(sx / d, sy / d);
    }
}

// Stage 3a (iterations 2-3): V-pass reading precomputed TV. LDS 19.6 KB.
__global__ __launch_bounds__(256) void k_etf_v(const float2* __restrict__ tsrc,
                                               float2* __restrict__ tdst,
                                               const float* __restrict__ TV) {
#pragma clang fp contract(off)
    int ty  = threadIdx.x & 31;
    int txw = threadIdx.x >> 5;
    int y0 = blockIdx.x * VTY;
    int x0 = blockIdx.y * VTX;
    int b  = blockIdx.z;
    size_t base = (size_t)b * SX * SY;

    __shared__ __align__(16) float2 sT[VTX + 2 * MU][VTY];     // 26 x 32 f2 (6.5 KB)
    __shared__ __align__(16) float  sTV[5][VTX + MU][VTY];     // 5 x 21 x 32 (13.1 KB)

    int tid = threadIdx.x;
    for (int i = tid; i < (VTX + 2 * MU) * (VTY / 4) * 2; i += 256) {
        int r = i >> 4;
        int c = i & 15;
        int gx = x0 - MU + r;
        if (gx >= 0 && gx < SX)
            ((float4*)&sT[r][0])[c] = ((const float4*)(tsrc + base + (size_t)gx * SY + y0))[c];
    }
    for (int i = tid; i < 5 * (VTX + MU) * (VTY / 4); i += 256) {
        int j   = i / ((VTX + MU) * (VTY / 4));
        int rem = i - j * ((VTX + MU) * (VTY / 4));
        int r   = rem >> 3;
        int c   = rem & 7;
        int gx  = x0 - MU + r;
        if (gx >= 0 && gx < SX)
            ((float4*)&sTV[j][r][0])[c] =
                ((const float4*)(TV + (size_t)j * NPIX + base + (size_t)gx * SY + y0))[c];
    }
    __syncthreads();

    int yi = y0 + ty;
#pragma unroll
    for (int sub = 0; sub < 2; ++sub) {
        int tx = txw + (sub << 3);
        int xi = x0 + tx;
        size_t idx = base + (size_t)xi * SY + yi;

        float2 ct = sT[tx + MU][ty];
        float sx = 0.0f, sy = 0.0f;
#pragma unroll
        for (int k = -MU; k <= MU; ++k) {
            int nx = xi + k;
            if (nx < 0 || nx >= SX) continue;
            float2 nt = sT[tx + MU + k][ty];
            float th;
            if (k > 0)      th =  sTV[k - 1][tx + MU][ty];
            else if (k < 0) th = -sTV[-k - 1][tx + MU + k][ty];
            else            th =  0.0f;
            float dot = (ct.x * nt.x) + (ct.y * nt.y);
            float w   = ((th + 1.0f) * dot) * 0.5f;
            sx = sx + (nt.x * w);
            sy = sy + (nt.y * w);
        }
        float n = sqrtf((sx * sx) + (sy * sy));
        float d = (n == 0.0f) ? 1.0f : n;
        tdst[idx] = make_float2(sx / d, sy / d);
    }
}

// Stage 3b (iterations 2-3): H-pass reading precomputed TH; DoG fused on last.
__global__ __launch_bounds__(256) void k_etf_h(const float2* __restrict__ tsrc,
                                               float2* __restrict__ tdst,
                                               const float* __restrict__ TH,
                                               const float* __restrict__ img,
                                               float* __restrict__ dogout,
                                               DogW dw, int do_dog) {
#pragma clang fp contract(off)
    int tid = threadIdx.x;
    int xi  = blockIdx.y;
    int b   = blockIdx.z;
    size_t base    = (size_t)b * SX * SY;
    size_t rowbase = base + (size_t)xi * SY;

    __shared__ __align__(16) float2 sT[SY];        // 4 KB
    __shared__ __align__(16) float  sTH[5][SY];    // 10 KB

    ((float4*)sT)[tid] = ((const float4*)(tsrc + rowbase))[tid];
    for (int i = tid; i < 5 * (SY / 4); i += 256) {
        int j = i >> 7;
        int c = i & 127;
        ((float4*)&sTH[0][0])[i] = ((const float4*)(TH + (size_t)j * NPIX + rowbase))[c];
    }
    __syncthreads();

#pragma unroll
    for (int half = 0; half < 2; ++half) {
        int yi = tid + half * 256;
        float2 ct = sT[yi];
        float sx = 0.0f, sy = 0.0f;
#pragma unroll
        for (int k = -MU; k <= MU; ++k) {
            int ny = yi + k;
            if (ny < 0 || ny >= SY) continue;
            float2 nt = sT[ny];
            float th;
            if (k > 0)      th =  sTH[k - 1][yi];
            else if (k < 0) th = -sTH[-k - 1][ny];
            else            th =  0.0f;
            float dot = (ct.x * nt.x) + (ct.y * nt.y);
            float w   = ((th + 1.0f) * dot) * 0.5f;
            sx = sx + (nt.x * w);
            sy = sy + (nt.y * w);
        }
        float n = sqrtf((sx * sx) + (sy * sy));
        float d = (n == 0.0f) ? 1.0f : n;
        float ex = sx / d;
        float ey = sy / d;
        tdst[rowbase + yi] = make_float2(ex, ey);

        if (do_dog) {
            float perx = -ey;
            float pery =  ex;
            float xf = (float)xi, yf = (float)yi;
            float acc = 0.0f;
#pragma unroll
            for (int t = -3; t <= 3; ++t) {
                float tf  = (float)t;
                float ptx = xf + (perx * tf);
                float pty = yf + (pery * tf);
                int px = (int)rintf(fminf(fmaxf(ptx, 0.0f), (float)(SX - 1)));
                int py = (int)rintf(fminf(fmaxf(pty, 0.0f), (float)(SY - 1)));
                float il = img[base + (size_t)px * SY + py];
                acc = acc + (il * dw.g[t + 3]);
            }
            dogout[rowbase + yi] = acc / dw.tw;
        }
    }
}

// Fallback ETF (inline ocml tanh) — only if workspace is too small.
__global__ void k_etf(const float2* __restrict__ tsrc, float2* __restrict__ tdst,
                      const float* __restrict__ mag, int vert) {
#pragma clang fp contract(off)
    int yi = blockIdx.x * blockDim.x + threadIdx.x;
    int xi = blockIdx.y;
    int b  = blockIdx.z;
    size_t base = (size_t)b * SX * SY;
    size_t idx  = base + (size_t)xi * SY + yi;

    float  cm = mag[idx];
    float2 ct = tsrc[idx];

    float sx = 0.0f, sy = 0.0f;
    for (int k = -MU; k <= MU; ++k) {
        int nx = xi + (vert ? k : 0);
        int ny = yi + (vert ? 0 : k);
        if (nx < 0 || nx >= SX || ny < 0 || ny >= SY) continue;
        size_t nidx = base + (size_t)nx * SY + ny;
        float  nm = mag[nidx];
        float2 nt = tsrc[nidx];
        float dot = (ct.x * nt.x) + (ct.y * nt.y);
        float th  = (float)tanh((double)(nm - cm));
        float w   = ((th + 1.0f) * dot) * 0.5f;
        sx = sx + (nt.x * w);
        sy = sy + (nt.y * w);
    }
    float n = sqrtf((sx * sx) + (sy * sy));
    float d = (n == 0.0f) ? 1.0f : n;
    tdst[idx] = make_float2(sx / d, sy / d);
}

// Fallback only: DoG along the perpendicular of the ETF
__global__ void k_dog(const float* __restrict__ img, const float2* __restrict__ etf,
                      float* __restrict__ dog, DogW w) {
#pragma clang fp contract(off)
    int yi = blockIdx.x * blockDim.x + threadIdx.x;
    int xi = blockIdx.y;
    int b  = blockIdx.z;
    size_t base = (size_t)b * SX * SY;
    size_t idx  = base + (size_t)xi * SY + yi;

    float2 e = etf[idx];
    float perx = -e.y;
    float pery =  e.x;
    float xf = (float)xi, yf = (float)yi;

    float acc = 0.0f;
#pragma unroll
    for (int t = -3; t <= 3; ++t) {
        float tf  = (float)t;
        float ptx = xf + (perx * tf);
        float pty = yf + (pery * tf);
        int px = (int)rintf(fminf(fmaxf(ptx, 0.0f), (float)(SX - 1)));
        int py = (int)rintf(fminf(fmaxf(pty, 0.0f), (float)(SY - 1)));
        float il = img[base + (size_t)px * SY + py];
        acc = acc + (il * w.g[t + 3]);
    }
    dog[idx] = acc / w.tw;
}

// Stage 5: FDoG. Two independent dependent-load chains walked interleaved.
__global__ void k_fdog(const float* __restrict__ dog, const float2* __restrict__ etf,
                       int* __restrict__ out, FdogW w) {
#pragma clang fp contract(off)
    int yi = blockIdx.x * blockDim.x + threadIdx.x;
    int xi = blockIdx.y;
    int b  = blockIdx.z;
    size_t base = (size_t)b * SX * SY;
    size_t idx  = base + (size_t)xi * SY + yi;

    float d1[9];
    float d2[10];
    float2 e0 = etf[idx];
    float2 e1 = e0, e2 = e0;
    int p1x = xi, p1y = yi;
    int p2x = xi, p2y = yi;
    d2[0] = dog[idx];

#pragma unroll
    for (int s = 1; s <= 9; ++s) {
        float fx1 = (float)p1x + (e1.x * -1.0f);
        float fy1 = (float)p1y + (e1.y * -1.0f);
        p1x = (int)rintf(fminf(fmaxf(fx1, 0.0f), (float)(SX - 1)));
        p1y = (int)rintf(fminf(fmaxf(fy1, 0.0f), (float)(SY - 1)));
        size_t i1 = base + (size_t)p1x * SY + p1y;
        float fx2 = (float)p2x + (e2.x * 1.0f);
        float fy2 = (float)p2y + (e2.y * 1.0f);
        p2x = (int)rintf(fminf(fmaxf(fx2, 0.0f), (float)(SX - 1)));
        p2y = (int)rintf(fminf(fmaxf(fy2, 0.0f), (float)(SY - 1)));
        size_t i2 = base + (size_t)p2x * SY + p2y;

        d1[s - 1] = dog[i1];
        d2[s]     = dog[i2];
        if (s < 9) {
            e1 = etf[i1];
            e2 = etf[i2];
        }
    }

    float acc = 0.0f;
#pragma unroll
    for (int s = 1; s <= 9; ++s) acc = acc + (d1[s - 1] * w.g[s]);
    acc = acc + (d2[0] * w.g[0]);
#pragma unroll
    for (int s = 1; s <= 9; ++s) acc = acc + (d2[s] * w.g[s]);

    float fv = acc / w.tw;
    float th = 1.0f + fast_tanh_f32(fv);
    out[idx] = ((fv < 0.0f) && (th < 0.7f)) ? 0 : 1;
}

static double gpdf(double v, double sig) {
    return exp(-(v * v) / (2.0 * sig * sig)) / (sqrt(2.0 * M_PI) * sig);
}

extern "C" void kernel_launch(void* const* d_in, const int* in_sizes, int n_in,
                              void* d_out, int out_size, void* d_ws, size_t ws_size,
                              hipStream_t stream) {
    const float* img = (const float*)d_in[0];
    int* out = (int*)d_out;
    char* ws = (char*)d_ws;

    // Fast-path workspace layout (60 MB + 2 KB + 4 B):
    //   mag [0,4MB) (dog reuses after iter-1) | tA [4,12) | tB [12,20)
    //   TV [20,40) | TH [40,60) | partial [60MB,+2KB) | maxbits [+4)
    const size_t need = (size_t)60 * MB + SOB_BLOCKS * sizeof(float) + 4;
    bool fast = ws_size >= need;

    float*  mag = (float*)(ws);
    float2* tA  = (float2*)(ws + (size_t)4  * MB);
    float2* tB  = (float2*)(ws + (size_t)12 * MB);
    float*  TV  = (float*)(ws + (size_t)20 * MB);
    float*  TH  = (float*)(ws + (size_t)40 * MB);
    size_t  tail = fast ? (size_t)60 * MB : (size_t)20 * MB;
    float*        partial = (float*)(ws + tail);
    unsigned int* maxbits = (unsigned int*)(ws + tail + SOB_BLOCKS * sizeof(float));

    dim3 blk(256, 1, 1);
    dim3 grd(SY / 256, SX, BN);
    dim3 vgrd(SY / VTY, SX / VTX, BN);
    dim3 hgrd(1, SX, BN);

    DogW dw;
    {
        double tw = 0.0;
        for (int t = -3; t <= 3; ++t) {
            double g = gpdf((double)t, 1.0) - 0.99 * gpdf((double)t, 1.6);
            dw.g[t + 3] = (float)g;
            tw += g;
        }
        dw.tw = (float)tw;
    }
    FdogW fw;
    {
        for (int s = 0; s <= 9; ++s) fw.g[s] = (float)gpdf((double)s, 3.0);
        double tw = 0.0;
        for (int s = 1; s <= 9; ++s) tw += gpdf((double)s, 3.0);
        for (int s = 0; s <= 9; ++s) tw += gpdf((double)s, 3.0);
        fw.tw = (float)tw;
    }

    k_sobel<<<dim3(SOB_BLOCKS, 1, 1), blk, 0, stream>>>(img, mag, tA, partial);

    float2* src = tA;
    float2* dst = tB;
    if (fast) {
        float* dogbuf = mag;   // mag is dead after iteration 1; reuse as DoG output
        // iteration 1: tanh-plane build fused into V and H
        k_etf_v1<<<vgrd, blk, 0, stream>>>(src, dst, mag, partial, TV);
        { float2* t = src; src = dst; dst = t; }
        k_etf_h1<<<hgrd, blk, 0, stream>>>(src, dst, mag, partial, TH);
        { float2* t = src; src = dst; dst = t; }
        // iterations 2-3: read precomputed TV/TH; DoG fused into last H
        for (int it = 1; it < 3; ++it) {
            k_etf_v<<<vgrd, blk, 0, stream>>>(src, dst, TV);
            { float2* t = src; src = dst; dst = t; }
            k_etf_h<<<hgrd, blk, 0, stream>>>(src, dst, TH, img, dogbuf, dw, it == 2);
            { float2* t = src; src = dst; dst = t; }
        }
        // src holds final ETF; dogbuf holds DoG
        k_fdog<<<grd, blk, 0, stream>>>(dogbuf, src, out, fw);
    } else {
        k_reduce<<<1, 256, 0, stream>>>(partial, maxbits);
        k_norm<<<NPIX / 256, 256, 0, stream>>>(mag, maxbits);
        for (int it = 0; it < 3; ++it) {
            k_etf<<<grd, blk, 0, stream>>>(src, dst, mag, 1);
            { float2* t = src; src = dst; dst = t; }
            k_etf<<<grd, blk, 0, stream>>>(src, dst, mag, 0);
            { float2* t = src; src = dst; dst = t; }
        }
        float* dogbuf = (src == tA) ? (float*)tB : (float*)tA;
        k_dog<<<grd, blk, 0, stream>>>(img, src, dogbuf, dw);
        k_fdog<<<grd, blk, 0, stream>>>(dogbuf, src, out, fw);
    }
}

// Round 7
// 190.150 us; speedup vs baseline: 1.0220x; 1.0220x over previous
//
#include <hip/hip_runtime.h>
#include <math.h>

#pragma clang fp contract(off)

#define BN 4
#define SX 512
#define SY 512
#define NPIX (BN * SX * SY)
#define MU 5
#define MB (1024 * 1024)
#define SOB_BLOCKS (NPIX / 2048)   // 512 sobel blocks (8 px/thread)

struct DogW  { float g[7];  float tw; };
struct FdogW { float g[10]; float tw; };

// tanh via expm1 identity: tanh(d) = expm1(2|d|) / (expm1(2|d|) + 2), odd.
__device__ __forceinline__ float fast_tanh_f32(float dF) {
    double d = (double)dF;
    double y = fabs(d);
    double t = expm1(2.0 * y);
    double r = t / (t + 2.0);
    if (y > 350.0) r = 1.0;
    return (float)copysign(r, d);
}

__device__ __forceinline__ float img_at(const float* __restrict__ img, int b, int x, int y) {
    if (x < 0 || x >= SX || y < 0 || y >= SY) return 0.0f;
    return img[(size_t)b * SX * SY + (size_t)x * SY + y];
}

// Stage 1: Sobel -> mag (unnormalized), initial tangent, per-block max.
// 8 px/thread: 6 float4 row loads + 6 guarded scalars = 1.31 ld/px, 2x ILP.
// Per-pixel expression order identical to scalar version -> bit-exact.
// NOTE: first kernel absorbs the harness 256MB poison writeback drain.
__global__ __launch_bounds__(256) void k_sobel(const float* __restrict__ img,
                                               float* __restrict__ mag,
                                               float2* __restrict__ tang,
                                               float* __restrict__ partial) {
#pragma clang fp contract(off)
    int tid = threadIdx.x;
    size_t pixbase = (size_t)blockIdx.x * 2048 + (size_t)tid * 8;
    int b  = (int)(pixbase >> 18);          // / (512*512)
    int p  = (int)(pixbase & 262143);
    int xi = p >> 9;
    int yi = p & 511;                        // multiple of 8
    size_t base = (size_t)b * SX * SY;
    size_t idx  = base + (size_t)xi * SY + yi;

    bool xm = (xi - 1 >= 0);
    bool xp = (xi + 1 < SX);
    const float* rowm = img + base + (size_t)(xi - 1) * SY;
    const float* row0 = img + base + (size_t)xi * SY;
    const float* rowp = img + base + (size_t)(xi + 1) * SY;

    float4 a4a = make_float4(0.f,0.f,0.f,0.f), a4b = make_float4(0.f,0.f,0.f,0.f);
    float4 c4a = make_float4(0.f,0.f,0.f,0.f), c4b = make_float4(0.f,0.f,0.f,0.f);
    float4 b4a = *(const float4*)(row0 + yi);
    float4 b4b = *(const float4*)(row0 + yi + 4);
    if (xm) { a4a = *(const float4*)(rowm + yi); a4b = *(const float4*)(rowm + yi + 4); }
    if (xp) { c4a = *(const float4*)(rowp + yi); c4b = *(const float4*)(rowp + yi + 4); }

    float aL = 0.f, aR = 0.f, bL = 0.f, bR = 0.f, cL = 0.f, cR = 0.f;
    if (yi > 0) {
        bL = row0[yi - 1];
        if (xm) aL = rowm[yi - 1];
        if (xp) cL = rowp[yi - 1];
    }
    if (yi + 8 < SY) {
        bR = row0[yi + 8];
        if (xm) aR = rowm[yi + 8];
        if (xp) cR = rowp[yi + 8];
    }

    float a[10]  = { aL, a4a.x, a4a.y, a4a.z, a4a.w, a4b.x, a4b.y, a4b.z, a4b.w, aR };
    float bb[10] = { bL, b4a.x, b4a.y, b4a.z, b4a.w, b4b.x, b4b.y, b4b.z, b4b.w, bR };
    float c[10]  = { cL, c4a.x, c4a.y, c4a.z, c4a.w, c4b.x, c4b.y, c4b.z, c4b.w, cR };

    float m8[8];
    float tg[16];
    float wm = 0.0f;
#pragma unroll
    for (int j = 0; j < 8; ++j) {
        float v00 = a[j];
        float v01 = a[j + 1];
        float v02 = a[j + 2];
        float v10 = bb[j];
        float v12 = bb[j + 2];
        float v20 = c[j];
        float v21 = c[j + 1];
        float v22 = c[j + 2];

        float s0 = (-1.0f * v00);
        s0 = s0 + (-2.0f * v01);
        s0 = s0 + (-1.0f * v02);
        s0 = s0 + ( 1.0f * v20);
        s0 = s0 + ( 2.0f * v21);
        s0 = s0 + ( 1.0f * v22);
        float s1 = (-1.0f * v00);
        s1 = s1 + ( 1.0f * v02);
        s1 = s1 + (-2.0f * v10);
        s1 = s1 + ( 2.0f * v12);
        s1 = s1 + (-1.0f * v20);
        s1 = s1 + ( 1.0f * v22);

        float m = sqrtf((s0 * s0) + (s1 * s1));
        float tx = -s1, ty = s0;
        float n = sqrtf((tx * tx) + (ty * ty));
        float d = (n == 0.0f) ? 1.0f : n;
        m8[j] = m;
        tg[2 * j]     = tx / d;
        tg[2 * j + 1] = ty / d;
        wm = fmaxf(wm, m);
    }
    ((float4*)(mag + idx))[0] = make_float4(m8[0], m8[1], m8[2], m8[3]);
    ((float4*)(mag + idx))[1] = make_float4(m8[4], m8[5], m8[6], m8[7]);
#pragma unroll
    for (int q = 0; q < 4; ++q)
        ((float4*)(tang + idx))[q] = make_float4(tg[4*q], tg[4*q+1], tg[4*q+2], tg[4*q+3]);

    for (int off = 32; off > 0; off >>= 1) wm = fmaxf(wm, __shfl_down(wm, off, 64));
    __shared__ float red[4];
    int lane = tid & 63;
    int wid  = tid >> 6;
    if (lane == 0) red[wid] = wm;
    __syncthreads();
    if (tid == 0)
        partial[blockIdx.x] = fmaxf(fmaxf(red[0], red[1]), fmaxf(red[2], red[3]));
}

// Fallback only: reduce partials -> global max bits (one block).
__global__ void k_reduce(const float* __restrict__ partial, unsigned int* __restrict__ maxbits) {
    float m = 0.0f;
    for (int i = threadIdx.x; i < SOB_BLOCKS; i += 256) m = fmaxf(m, partial[i]);
    for (int off = 32; off > 0; off >>= 1) m = fmaxf(m, __shfl_down(m, off, 64));
    __shared__ float red[4];
    int lane = threadIdx.x & 63;
    int wid  = threadIdx.x >> 6;
    if (lane == 0) red[wid] = m;
    __syncthreads();
    if (threadIdx.x == 0) {
        float bm = fmaxf(fmaxf(red[0], red[1]), fmaxf(red[2], red[3]));
        *maxbits = __float_as_uint(bm);
    }
}

// Fallback only: mag /= max(mag)
__global__ void k_norm(float* __restrict__ mag, const unsigned int* __restrict__ maxbits) {
    int i = blockIdx.x * blockDim.x + threadIdx.x;
    float mx = __uint_as_float(*maxbits);
    mag[i] = mag[i] / mx;
}

// Stage 2+3 fused: every block redundantly reduces the 512 partials (L2-hit,
// ~1us overlapped) -> mx in-register; then tanh difference fields with
// normalization fused. fmax is exact -> mx bit-identical to 1-block reduce.
__global__ void k_tanh(const float* __restrict__ mag, const float* __restrict__ partial,
                       float* __restrict__ TV, float* __restrict__ TH) {
#pragma clang fp contract(off)
    int tid = threadIdx.x;
    float m2 = 0.0f;
    for (int i = tid; i < SOB_BLOCKS; i += 256) m2 = fmaxf(m2, partial[i]);
    for (int off = 32; off > 0; off >>= 1) m2 = fmaxf(m2, __shfl_down(m2, off, 64));
    __shared__ float red[4];
    int lane = tid & 63;
    int wid  = tid >> 6;
    if (lane == 0) red[wid] = m2;
    __syncthreads();
    const float mx = fmaxf(fmaxf(red[0], red[1]), fmaxf(red[2], red[3]));

    int yi = blockIdx.x * blockDim.x + tid;
    int xi = blockIdx.y;
    int b  = blockIdx.z;
    size_t base = (size_t)b * SX * SY;
    size_t idx  = base + (size_t)xi * SY + yi;
    float cm = mag[idx] / mx;
#pragma unroll
    for (int k = 1; k <= 5; ++k) {
        if (xi + k < SX) {
            float nm = mag[idx + (size_t)k * SY] / mx;
            TV[(size_t)(k - 1) * NPIX + idx] = fast_tanh_f32(nm - cm);
        }
    }
#pragma unroll
    for (int k = 1; k <= 5; ++k) {
        if (yi + k < SY) {
            float nm = mag[idx + k] / mx;
            TH[(size_t)(k - 1) * NPIX + idx] = fast_tanh_f32(nm - cm);
        }
    }
}

// Stage 3a: V-pass. Tile 32(y) x 16(x); 256 threads, 2 output rows/thread.
// LDS = 19.6 KB -> full 32-wave occupancy; halo: tsrc 1.63x, TV 1.31x.
#define VTY 32
#define VTX 16
__global__ __launch_bounds__(256) void k_etf_v(const float2* __restrict__ tsrc,
                                               float2* __restrict__ tdst,
                                               const float* __restrict__ TV) {
#pragma clang fp contract(off)
    int ty  = threadIdx.x & 31;
    int txw = threadIdx.x >> 5;
    int y0 = blockIdx.x * VTY;
    int x0 = blockIdx.y * VTX;
    int b  = blockIdx.z;
    size_t base = (size_t)b * SX * SY;

    __shared__ __align__(16) float2 sT[VTX + 2 * MU][VTY];     // 26 x 32 f2 (6.5 KB)
    __shared__ __align__(16) float  sTV[5][VTX + MU][VTY];     // 5 x 21 x 32 (13.1 KB)

    int tid = threadIdx.x;
    for (int i = tid; i < (VTX + 2 * MU) * (VTY / 4) * 2; i += 256) {
        int r = i >> 4;
        int c = i & 15;
        int gx = x0 - MU + r;
        if (gx >= 0 && gx < SX)
            ((float4*)&sT[r][0])[c] = ((const float4*)(tsrc + base + (size_t)gx * SY + y0))[c];
    }
    for (int i = tid; i < 5 * (VTX + MU) * (VTY / 4); i += 256) {
        int j   = i / ((VTX + MU) * (VTY / 4));
        int rem = i - j * ((VTX + MU) * (VTY / 4));
        int r   = rem >> 3;
        int c   = rem & 7;
        int gx  = x0 - MU + r;
        if (gx >= 0 && gx < SX)
            ((float4*)&sTV[j][r][0])[c] =
                ((const float4*)(TV + (size_t)j * NPIX + base + (size_t)gx * SY + y0))[c];
    }
    __syncthreads();

    int yi = y0 + ty;
#pragma unroll
    for (int sub = 0; sub < 2; ++sub) {
        int tx = txw + (sub << 3);
        int xi = x0 + tx;
        size_t idx = base + (size_t)xi * SY + yi;

        float2 ct = sT[tx + MU][ty];
        float sx = 0.0f, sy = 0.0f;
#pragma unroll
        for (int k = -MU; k <= MU; ++k) {
            int nx = xi + k;
            if (nx < 0 || nx >= SX) continue;
            float2 nt = sT[tx + MU + k][ty];
            float th;
            if (k > 0)      th =  sTV[k - 1][tx + MU][ty];
            else if (k < 0) th = -sTV[-k - 1][tx + MU + k][ty];
            else            th =  0.0f;
            float dot = (ct.x * nt.x) + (ct.y * nt.y);
            float w   = ((th + 1.0f) * dot) * 0.5f;
            sx = sx + (nt.x * w);
            sy = sy + (nt.y * w);
        }
        float n = sqrtf((sx * sx) + (sy * sy));
        float d = (n == 0.0f) ? 1.0f : n;
        tdst[idx] = make_float2(sx / d, sy / d);
    }
}

// Stage 3b: H-pass. One block per image row; DoG fused on last iteration.
__global__ __launch_bounds__(256) void k_etf_h(const float2* __restrict__ tsrc,
                                               float2* __restrict__ tdst,
                                               const float* __restrict__ TH,
                                               const float* __restrict__ img,
                                               float* __restrict__ dogout,
                                               DogW dw, int do_dog) {
#pragma clang fp contract(off)
    int tid = threadIdx.x;
    int xi  = blockIdx.y;
    int b   = blockIdx.z;
    size_t base    = (size_t)b * SX * SY;
    size_t rowbase = base + (size_t)xi * SY;

    __shared__ __align__(16) float2 sT[SY];        // 4 KB
    __shared__ __align__(16) float  sTH[5][SY];    // 10 KB

    ((float4*)sT)[tid] = ((const float4*)(tsrc + rowbase))[tid];
    for (int i = tid; i < 5 * (SY / 4); i += 256) {
        int j = i >> 7;
        int c = i & 127;
        ((float4*)&sTH[0][0])[i] = ((const float4*)(TH + (size_t)j * NPIX + rowbase))[c];
    }
    __syncthreads();

#pragma unroll
    for (int half = 0; half < 2; ++half) {
        int yi = tid + half * 256;
        float2 ct = sT[yi];
        float sx = 0.0f, sy = 0.0f;
#pragma unroll
        for (int k = -MU; k <= MU; ++k) {
            int ny = yi + k;
            if (ny < 0 || ny >= SY) continue;
            float2 nt = sT[ny];
            float th;
            if (k > 0)      th =  sTH[k - 1][yi];
            else if (k < 0) th = -sTH[-k - 1][ny];
            else            th =  0.0f;
            float dot = (ct.x * nt.x) + (ct.y * nt.y);
            float w   = ((th + 1.0f) * dot) * 0.5f;
            sx = sx + (nt.x * w);
            sy = sy + (nt.y * w);
        }
        float n = sqrtf((sx * sx) + (sy * sy));
        float d = (n == 0.0f) ? 1.0f : n;
        float ex = sx / d;
        float ey = sy / d;
        tdst[rowbase + yi] = make_float2(ex, ey);

        if (do_dog) {
            float perx = -ey;
            float pery =  ex;
            float xf = (float)xi, yf = (float)yi;
            float acc = 0.0f;
#pragma unroll
            for (int t = -3; t <= 3; ++t) {
                float tf  = (float)t;
                float ptx = xf + (perx * tf);
                float pty = yf + (pery * tf);
                int px = (int)rintf(fminf(fmaxf(ptx, 0.0f), (float)(SX - 1)));
                int py = (int)rintf(fminf(fmaxf(pty, 0.0f), (float)(SY - 1)));
                float il = img[base + (size_t)px * SY + py];
                acc = acc + (il * dw.g[t + 3]);
            }
            dogout[rowbase + yi] = acc / dw.tw;
        }
    }
}

// Fallback ETF (inline ocml tanh) — only if workspace is too small.
__global__ void k_etf(const float2* __restrict__ tsrc, float2* __restrict__ tdst,
                      const float* __restrict__ mag, int vert) {
#pragma clang fp contract(off)
    int yi = blockIdx.x * blockDim.x + threadIdx.x;
    int xi = blockIdx.y;
    int b  = blockIdx.z;
    size_t base = (size_t)b * SX * SY;
    size_t idx  = base + (size_t)xi * SY + yi;

    float  cm = mag[idx];
    float2 ct = tsrc[idx];

    float sx = 0.0f, sy = 0.0f;
    for (int k = -MU; k <= MU; ++k) {
        int nx = xi + (vert ? k : 0);
        int ny = yi + (vert ? 0 : k);
        if (nx < 0 || nx >= SX || ny < 0 || ny >= SY) continue;
        size_t nidx = base + (size_t)nx * SY + ny;
        float  nm = mag[nidx];
        float2 nt = tsrc[nidx];
        float dot = (ct.x * nt.x) + (ct.y * nt.y);
        float th  = (float)tanh((double)(nm - cm));
        float w   = ((th + 1.0f) * dot) * 0.5f;
        sx = sx + (nt.x * w);
        sy = sy + (nt.y * w);
    }
    float n = sqrtf((sx * sx) + (sy * sy));
    float d = (n == 0.0f) ? 1.0f : n;
    tdst[idx] = make_float2(sx / d, sy / d);
}

// Fallback only: DoG along the perpendicular of the ETF
__global__ void k_dog(const float* __restrict__ img, const float2* __restrict__ etf,
                      float* __restrict__ dog, DogW w) {
#pragma clang fp contract(off)
    int yi = blockIdx.x * blockDim.x + threadIdx.x;
    int xi = blockIdx.y;
    int b  = blockIdx.z;
    size_t base = (size_t)b * SX * SY;
    size_t idx  = base + (size_t)xi * SY + yi;

    float2 e = etf[idx];
    float perx = -e.y;
    float pery =  e.x;
    float xf = (float)xi, yf = (float)yi;

    float acc = 0.0f;
#pragma unroll
    for (int t = -3; t <= 3; ++t) {
        float tf  = (float)t;
        float ptx = xf + (perx * tf);
        float pty = yf + (pery * tf);
        int px = (int)rintf(fminf(fmaxf(ptx, 0.0f), (float)(SX - 1)));
        int py = (int)rintf(fminf(fmaxf(pty, 0.0f), (float)(SY - 1)));
        float il = img[base + (size_t)px * SY + py];
        acc = acc + (il * w.g[t + 3]);
    }
    dog[idx] = acc / w.tw;
}

// Stage 5: FDoG. Two independent dependent-load chains walked interleaved.
__global__ void k_fdog(const float* __restrict__ dog, const float2* __restrict__ etf,
                       int* __restrict__ out, FdogW w) {
#pragma clang fp contract(off)
    int yi = blockIdx.x * blockDim.x + threadIdx.x;
    int xi = blockIdx.y;
    int b  = blockIdx.z;
    size_t base = (size_t)b * SX * SY;
    size_t idx  = base + (size_t)xi * SY + yi;

    float d1[9];
    float d2[10];
    float2 e0 = etf[idx];
    float2 e1 = e0, e2 = e0;
    int p1x = xi, p1y = yi;
    int p2x = xi, p2y = yi;
    d2[0] = dog[idx];

#pragma unroll
    for (int s = 1; s <= 9; ++s) {
        float fx1 = (float)p1x + (e1.x * -1.0f);
        float fy1 = (float)p1y + (e1.y * -1.0f);
        p1x = (int)rintf(fminf(fmaxf(fx1, 0.0f), (float)(SX - 1)));
        p1y = (int)rintf(fminf(fmaxf(fy1, 0.0f), (float)(SY - 1)));
        size_t i1 = base + (size_t)p1x * SY + p1y;
        float fx2 = (float)p2x + (e2.x * 1.0f);
        float fy2 = (float)p2y + (e2.y * 1.0f);
        p2x = (int)rintf(fminf(fmaxf(fx2, 0.0f), (float)(SX - 1)));
        p2y = (int)rintf(fminf(fmaxf(fy2, 0.0f), (float)(SY - 1)));
        size_t i2 = base + (size_t)p2x * SY + p2y;

        d1[s - 1] = dog[i1];
        d2[s]     = dog[i2];
        if (s < 9) {
            e1 = etf[i1];
            e2 = etf[i2];
        }
    }

    float acc = 0.0f;
#pragma unroll
    for (int s = 1; s <= 9; ++s) acc = acc + (d1[s - 1] * w.g[s]);
    acc = acc + (d2[0] * w.g[0]);
#pragma unroll
    for (int s = 1; s <= 9; ++s) acc = acc + (d2[s] * w.g[s]);

    float fv = acc / w.tw;
    float th = 1.0f + fast_tanh_f32(fv);
    out[idx] = ((fv < 0.0f) && (th < 0.7f)) ? 0 : 1;
}

static double gpdf(double v, double sig) {
    return exp(-(v * v) / (2.0 * sig * sig)) / (sqrt(2.0 * M_PI) * sig);
}

extern "C" void kernel_launch(void* const* d_in, const int* in_sizes, int n_in,
                              void* d_out, int out_size, void* d_ws, size_t ws_size,
                              hipStream_t stream) {
    const float* img = (const float*)d_in[0];
    int* out = (int*)d_out;
    char* ws = (char*)d_ws;

    // Fast-path workspace layout (60 MB + 2 KB + 4 B):
    //   mag [0,4MB) (dog reuses after k_tanh) | tA [4,12) | tB [12,20)
    //   TV [20,40) | TH [40,60) | partial [60MB,+2KB) | maxbits [+4)
    const size_t need = (size_t)60 * MB + SOB_BLOCKS * sizeof(float) + 4;
    bool fast = ws_size >= need;

    float*  mag = (float*)(ws);
    float2* tA  = (float2*)(ws + (size_t)4  * MB);
    float2* tB  = (float2*)(ws + (size_t)12 * MB);
    float*  TV  = (float*)(ws + (size_t)20 * MB);
    float*  TH  = (float*)(ws + (size_t)40 * MB);
    size_t  tail = fast ? (size_t)60 * MB : (size_t)20 * MB;
    float*        partial = (float*)(ws + tail);
    unsigned int* maxbits = (unsigned int*)(ws + tail + SOB_BLOCKS * sizeof(float));

    dim3 blk(256, 1, 1);
    dim3 grd(SY / 256, SX, BN);
    dim3 vgrd(SY / VTY, SX / VTX, BN);
    dim3 hgrd(1, SX, BN);

    DogW dw;
    {
        double tw = 0.0;
        for (int t = -3; t <= 3; ++t) {
            double g = gpdf((double)t, 1.0) - 0.99 * gpdf((double)t, 1.6);
            dw.g[t + 3] = (float)g;
            tw += g;
        }
        dw.tw = (float)tw;
    }
    FdogW fw;
    {
        for (int s = 0; s <= 9; ++s) fw.g[s] = (float)gpdf((double)s, 3.0);
        double tw = 0.0;
        for (int s = 1; s <= 9; ++s) tw += gpdf((double)s, 3.0);
        for (int s = 0; s <= 9; ++s) tw += gpdf((double)s, 3.0);
        fw.tw = (float)tw;
    }

    k_sobel<<<dim3(SOB_BLOCKS, 1, 1), blk, 0, stream>>>(img, mag, tA, partial);

    float2* src = tA;
    float2* dst = tB;
    if (fast) {
        float* dogbuf = mag;   // mag is dead after k_tanh; reuse as DoG output
        k_tanh<<<grd, blk, 0, stream>>>(mag, partial, TV, TH);
        for (int it = 0; it < 3; ++it) {
            k_etf_v<<<vgrd, blk, 0, stream>>>(src, dst, TV);
            { float2* t = src; src = dst; dst = t; }
            k_etf_h<<<hgrd, blk, 0, stream>>>(src, dst, TH, img, dogbuf, dw, it == 2);
            { float2* t = src; src = dst; dst = t; }
        }
        // src holds final ETF; dogbuf holds DoG
        k_fdog<<<grd, blk, 0, stream>>>(dogbuf, src, out, fw);
    } else {
        k_reduce<<<1, 256, 0, stream>>>(partial, maxbits);
        k_norm<<<NPIX / 256, 256, 0, stream>>>(mag, maxbits);
        for (int it = 0; it < 3; ++it) {
            k_etf<<<grd, blk, 0, stream>>>(src, dst, mag, 1);
            { float2* t = src; src = dst; dst = t; }
            k_etf<<<grd, blk, 0, stream>>>(src, dst, mag, 0);
            { float2* t = src; src = dst; dst = t; }
        }
        float* dogbuf = (src == tA) ? (float*)tB : (float*)tA;
        k_dog<<<grd, blk, 0, stream>>>(img, src, dogbuf, dw);
        k_fdog<<<grd, blk, 0, stream>>>(dogbuf, src, out, fw);
    }
}